// Round 2
// baseline (541.239 us; speedup 1.0000x reference)
//
#include <hip/hip_runtime.h>
#include <math.h>

typedef __bf16 bf16_t;
typedef bf16_t bf16x8 __attribute__((ext_vector_type(8)));
typedef float  floatx4 __attribute__((ext_vector_type(4)));

#define MFMA_BF16(a, b, c) __builtin_amdgcn_mfma_f32_16x16x32_bf16((a), (b), (c), 0, 0, 0)

static constexpr int DMODEL = 1024;
static constexpr int NHEAD  = 16;
static constexpr int HDIM   = 64;
static constexpr int NBATCH = 4;
static constexpr int SEQLEN = 1024;
static constexpr int NTOK   = NBATCH * SEQLEN;  // 4096

__device__ __forceinline__ float rmax16(float x) {
#pragma unroll
    for (int m = 8; m >= 1; m >>= 1) x = fmaxf(x, __shfl_xor(x, m));
    return x;
}
__device__ __forceinline__ float rsum16(float x) {
#pragma unroll
    for (int m = 8; m >= 1; m >>= 1) x += __shfl_xor(x, m);
    return x;
}

// load 8 consecutive fp32, round to bf16x8 fragment
__device__ __forceinline__ bf16x8 load_cvt8(const float* __restrict__ p) {
    floatx4 a = *(const floatx4*)p;
    floatx4 b = *(const floatx4*)(p + 4);
    bf16x8 r;
    r[0] = (bf16_t)a[0]; r[1] = (bf16_t)a[1]; r[2] = (bf16_t)a[2]; r[3] = (bf16_t)a[3];
    r[4] = (bf16_t)b[0]; r[5] = (bf16_t)b[1]; r[6] = (bf16_t)b[2]; r[7] = (bf16_t)b[3];
    return r;
}

// ---------------- weight transpose+convert: Wt[n][k] = bf16(W[k][n]), 4 mats ----------------
__global__ __launch_bounds__(256) void transpose_w(
    const float* __restrict__ W0, const float* __restrict__ W1,
    const float* __restrict__ W2, const float* __restrict__ W3,
    bf16_t* __restrict__ out)
{
    __shared__ float tile[32][33];
    const float* W = (blockIdx.z == 0) ? W0 : (blockIdx.z == 1) ? W1
                   : (blockIdx.z == 2) ? W2 : W3;
    bf16_t* O = out + (size_t)blockIdx.z * DMODEL * DMODEL;
    int tx = threadIdx.x, ty = threadIdx.y;           // 32 x 8
    int r0 = blockIdx.x * 32, c0 = blockIdx.y * 32;
#pragma unroll
    for (int i = 0; i < 32; i += 8)
        tile[ty + i][tx] = W[(size_t)(r0 + ty + i) * DMODEL + c0 + tx];
    __syncthreads();
#pragma unroll
    for (int i = 0; i < 32; i += 8)
        O[(size_t)(c0 + ty + i) * DMODEL + r0 + tx] = (bf16_t)tile[tx][ty + i];
}

// ---------------- fused QKV projection GEMM ----------------
// X fp32 [4096,1024] @ W + b.  Wt is bf16 transposed ([out][in]).
// mode 0: Q -> [B,H,S,Dk] bf16, pre-scaled by 1/8 (exact pow2)
// mode 1: K -> [B,H,S,Dk] bf16
// mode 2: V -> [B,H,Dk,S] bf16 (transposed for PV MFMA B-fragments)
__global__ __launch_bounds__(256) void proj_qkv(
    const float* __restrict__ qin, const float* __restrict__ kin, const float* __restrict__ vin,
    const bf16_t* __restrict__ Wt,
    const float* __restrict__ bq, const float* __restrict__ bk, const float* __restrict__ bv,
    bf16_t* __restrict__ Qh, bf16_t* __restrict__ Kh, bf16_t* __restrict__ Vt)
{
    const int mode = blockIdx.z;
    const float* X     = (mode == 0) ? qin : (mode == 1) ? kin : vin;
    const bf16_t* W    = Wt + (size_t)mode * DMODEL * DMODEL;
    const float* bias  = (mode == 0) ? bq : (mode == 1) ? bk : bv;
    bf16_t* out        = (mode == 0) ? Qh : (mode == 1) ? Kh : Vt;

    const int wave = threadIdx.x >> 6, lane = threadIdx.x & 63;
    const int quad = lane >> 4, l15 = lane & 15;
    const int row0 = blockIdx.x * 64 + (wave & 1) * 32;
    const int col0 = blockIdx.y * 64 + (wave >> 1) * 32;

    const floatx4 zero = {0.f, 0.f, 0.f, 0.f};
    floatx4 acc[2][2];
    acc[0][0] = zero; acc[0][1] = zero; acc[1][0] = zero; acc[1][1] = zero;

    const float*  Abase = X + quad * 8;
    const bf16_t* Bbase = W + quad * 8;

#pragma unroll 2
    for (int k0 = 0; k0 < DMODEL; k0 += 32) {
        bf16x8 aF[2], bF[2];
#pragma unroll
        for (int mt = 0; mt < 2; mt++)
            aF[mt] = load_cvt8(Abase + (size_t)(row0 + mt * 16 + l15) * DMODEL + k0);
#pragma unroll
        for (int nt = 0; nt < 2; nt++)
            bF[nt] = *(const bf16x8*)(Bbase + (size_t)(col0 + nt * 16 + l15) * DMODEL + k0);
#pragma unroll
        for (int mt = 0; mt < 2; mt++)
#pragma unroll
            for (int nt = 0; nt < 2; nt++)
                acc[mt][nt] = MFMA_BF16(aF[mt], bF[nt], acc[mt][nt]);
    }

#pragma unroll
    for (int mt = 0; mt < 2; mt++) {
#pragma unroll
        for (int nt = 0; nt < 2; nt++) {
            const int col = col0 + nt * 16 + l15;
            const float bb = bias[col];
            const int hh = col >> 6, dd = col & 63;
#pragma unroll
            for (int r = 0; r < 4; r++) {
                const int tok = row0 + mt * 16 + quad * 4 + r;
                const int b = tok >> 10, s = tok & 1023;
                float vv = acc[mt][nt][r] + bb;
                size_t addr;
                if (mode == 2) {
                    addr = ((size_t)((b * NHEAD + hh) * HDIM + dd)) * SEQLEN + s;
                } else {
                    if (mode == 0) vv *= 0.125f;  // 1/sqrt(Dk)
                    addr = ((size_t)((b * NHEAD + hh) * SEQLEN + s)) * HDIM + dd;
                }
                out[addr] = (bf16_t)vv;
            }
        }
    }
}

// ---------------- causal flash attention (bf16 in, bf16 out) ----------------
// grid: (S/64, B*H); 4 waves/block, each wave owns 16 query rows.
__global__ __launch_bounds__(256) void attn(
    const bf16_t* __restrict__ Qh, const bf16_t* __restrict__ Kh,
    const bf16_t* __restrict__ Vt, bf16_t* __restrict__ X)
{
    __shared__ __align__(16) bf16_t plds[4][16 * 40];  // per-wave P tile, stride 40 pad
    const int wave = threadIdx.x >> 6, lane = threadIdx.x & 63;
    const int quad = lane >> 4, l15 = lane & 15;
    const int bh = blockIdx.y;
    const int b = bh >> 4, h = bh & 15;
    const int qbase = blockIdx.x * 64 + wave * 16;
    const bf16_t* Qp = Qh + (size_t)bh * SEQLEN * HDIM;
    const bf16_t* Kp = Kh + (size_t)bh * SEQLEN * HDIM;
    const bf16_t* Vp = Vt + (size_t)bh * HDIM * SEQLEN;
    bf16_t* pl = plds[wave];

    bf16x8 aQ[2];
#pragma unroll
    for (int c = 0; c < 2; c++)
        aQ[c] = *(const bf16x8*)(Qp + (size_t)(qbase + l15) * HDIM + c * 32 + quad * 8);

    const floatx4 zero = {0.f, 0.f, 0.f, 0.f};
    float m_r[4], l_r[4];
    floatx4 accO[4];
#pragma unroll
    for (int r = 0; r < 4; r++) { m_r[r] = -INFINITY; l_r[r] = 0.f; }
#pragma unroll
    for (int d4 = 0; d4 < 4; d4++) accO[d4] = zero;

    const int nk = (qbase + 47) >> 5;  // ceil((qbase+16)/32) key-chunks of 32
    for (int kc = 0; kc < nk; kc++) {
        const int kb = kc * 32;
        floatx4 S0 = zero, S1 = zero;
#pragma unroll
        for (int c = 0; c < 2; c++) {
            bf16x8 bK0 = *(const bf16x8*)(Kp + (size_t)(kb + l15) * HDIM + c * 32 + quad * 8);
            bf16x8 bK1 = *(const bf16x8*)(Kp + (size_t)(kb + 16 + l15) * HDIM + c * 32 + quad * 8);
            S0 = MFMA_BF16(aQ[c], bK0, S0);
            S1 = MFMA_BF16(aQ[c], bK1, S1);
        }
        const int k0c = kb + l15, k1c = kb + 16 + l15;
#pragma unroll
        for (int r = 0; r < 4; r++) {
            const int qrow = qbase + quad * 4 + r;
            float s0 = (k0c <= qrow) ? S0[r] : -1e30f;
            float s1 = (k1c <= qrow) ? S1[r] : -1e30f;
            float mx = rmax16(fmaxf(s0, s1));
            float mn = fmaxf(m_r[r], mx);
            float alpha = __expf(m_r[r] - mn);
            m_r[r] = mn;
            float p0 = __expf(s0 - mn);
            float p1 = __expf(s1 - mn);
            l_r[r] = l_r[r] * alpha + rsum16(p0 + p1);
#pragma unroll
            for (int dd = 0; dd < 4; dd++) accO[dd][r] *= alpha;
            pl[(quad * 4 + r) * 40 + l15]      = (bf16_t)p0;
            pl[(quad * 4 + r) * 40 + 16 + l15] = (bf16_t)p1;
        }
        // wave-private LDS round trip: P C-layout -> A-layout (in-order DS within a wave)
        bf16x8 aP = *(const bf16x8*)(pl + l15 * 40 + quad * 8);
#pragma unroll
        for (int dd = 0; dd < 4; dd++) {
            bf16x8 bV = *(const bf16x8*)(Vp + (size_t)(dd * 16 + l15) * SEQLEN + kb + quad * 8);
            accO[dd] = MFMA_BF16(aP, bV, accO[dd]);
        }
    }

#pragma unroll
    for (int dd = 0; dd < 4; dd++) {
        const int ch = h * HDIM + dd * 16 + l15;
#pragma unroll
        for (int r = 0; r < 4; r++) {
            const int srow = qbase + quad * 4 + r;
            float ov = accO[dd][r] / l_r[r];
            X[((size_t)(b * SEQLEN + srow)) * DMODEL + ch] = (bf16_t)ov;
        }
    }
}

// ---------------- output projection: bf16 X @ bf16 Wo^T + fp32 bias -> fp32 out ----------------
__global__ __launch_bounds__(256) void proj_o(
    const bf16_t* __restrict__ X, const bf16_t* __restrict__ Wt,
    const float* __restrict__ bias, float* __restrict__ out)
{
    const int wave = threadIdx.x >> 6, lane = threadIdx.x & 63;
    const int quad = lane >> 4, l15 = lane & 15;
    const int row0 = blockIdx.x * 64 + (wave & 1) * 32;
    const int col0 = blockIdx.y * 64 + (wave >> 1) * 32;

    const floatx4 zero = {0.f, 0.f, 0.f, 0.f};
    floatx4 acc[2][2];
    acc[0][0] = zero; acc[0][1] = zero; acc[1][0] = zero; acc[1][1] = zero;

    const bf16_t* Abase = X + quad * 8;
    const bf16_t* Bbase = Wt + quad * 8;

#pragma unroll 2
    for (int k0 = 0; k0 < DMODEL; k0 += 32) {
        bf16x8 aF[2], bF[2];
#pragma unroll
        for (int mt = 0; mt < 2; mt++)
            aF[mt] = *(const bf16x8*)(Abase + (size_t)(row0 + mt * 16 + l15) * DMODEL + k0);
#pragma unroll
        for (int nt = 0; nt < 2; nt++)
            bF[nt] = *(const bf16x8*)(Bbase + (size_t)(col0 + nt * 16 + l15) * DMODEL + k0);
#pragma unroll
        for (int mt = 0; mt < 2; mt++)
#pragma unroll
            for (int nt = 0; nt < 2; nt++)
                acc[mt][nt] = MFMA_BF16(aF[mt], bF[nt], acc[mt][nt]);
    }

#pragma unroll
    for (int mt = 0; mt < 2; mt++) {
#pragma unroll
        for (int nt = 0; nt < 2; nt++) {
            const int col = col0 + nt * 16 + l15;
            const float bb = bias[col];
#pragma unroll
            for (int r = 0; r < 4; r++) {
                const int tok = row0 + mt * 16 + quad * 4 + r;
                out[(size_t)tok * DMODEL + col] = acc[mt][nt][r] + bb;
            }
        }
    }
}

extern "C" void kernel_launch(void* const* d_in, const int* in_sizes, int n_in,
                              void* d_out, int out_size, void* d_ws, size_t ws_size,
                              hipStream_t stream)
{
    const float* q  = (const float*)d_in[0];
    const float* k  = (const float*)d_in[1];
    const float* v  = (const float*)d_in[2];
    // d_in[3] = causal mask (deterministic tril) — applied analytically
    const float* Wq = (const float*)d_in[4];
    const float* bq = (const float*)d_in[5];
    const float* Wk = (const float*)d_in[6];
    const float* bk = (const float*)d_in[7];
    const float* Wv = (const float*)d_in[8];
    const float* bv = (const float*)d_in[9];
    const float* Wo = (const float*)d_in[10];
    const float* bo = (const float*)d_in[11];
    float* out = (float*)d_out;

    char* ws = (char*)d_ws;
    const size_t WMAT = (size_t)DMODEL * DMODEL * sizeof(bf16_t);  // 2 MB
    const size_t TMAT = (size_t)NTOK * DMODEL * sizeof(bf16_t);    // 8 MB
    bf16_t* Wt = (bf16_t*)ws;                               // 4 x 2 MB (q,k,v,o transposed bf16)
    bf16_t* Qh = (bf16_t*)(ws + 4 * WMAT);                  // [B,H,S,Dk]
    bf16_t* Kh = (bf16_t*)(ws + 4 * WMAT + TMAT);           // [B,H,S,Dk]
    bf16_t* Vt = (bf16_t*)(ws + 4 * WMAT + 2 * TMAT);       // [B,H,Dk,S]
    bf16_t* Xa = (bf16_t*)(ws + 4 * WMAT + 3 * TMAT);       // [B,S,D] bf16

    transpose_w<<<dim3(32, 32, 4), dim3(32, 8), 0, stream>>>(Wq, Wk, Wv, Wo, Wt);
    proj_qkv<<<dim3(64, 16, 3), dim3(256), 0, stream>>>(q, k, v, Wt, bq, bk, bv, Qh, Kh, Vt);
    attn<<<dim3(16, 64), dim3(256), 0, stream>>>(Qh, Kh, Vt, Xa);
    proj_o<<<dim3(64, 16), dim3(256), 0, stream>>>(Xa, Wt + 3 * (size_t)DMODEL * DMODEL, bo, out);
}

// Round 3
// 319.572 us; speedup vs baseline: 1.6936x; 1.6936x over previous
//
#include <hip/hip_runtime.h>
#include <math.h>

typedef __bf16 bf16_t;
typedef bf16_t bf16x8 __attribute__((ext_vector_type(8)));
typedef bf16_t bf16x4 __attribute__((ext_vector_type(4)));
typedef float  floatx4 __attribute__((ext_vector_type(4)));

#define MFMA_BF16(a, b, c) __builtin_amdgcn_mfma_f32_16x16x32_bf16((a), (b), (c), 0, 0, 0)

static constexpr int DMODEL = 1024;
static constexpr int NHEAD  = 16;
static constexpr int HDIM   = 64;
static constexpr int NBATCH = 4;
static constexpr int SEQLEN = 1024;
static constexpr int NTOK   = NBATCH * SEQLEN;  // 4096

typedef __attribute__((address_space(3))) void       as3_void;
typedef __attribute__((address_space(1))) const void as1_cvoid;

// async global->LDS, 16B per lane; LDS dest = wave-uniform base + lane*16
__device__ __forceinline__ void gload16(const bf16_t* g, bf16_t* l) {
    __builtin_amdgcn_global_load_lds((as1_cvoid*)g, (as3_void*)l, 16, 0, 0);
}

// load 8 consecutive fp32, round to bf16x8
__device__ __forceinline__ bf16x8 load_cvt8(const float* __restrict__ p) {
    floatx4 a = *(const floatx4*)p;
    floatx4 b = *(const floatx4*)(p + 4);
    bf16x8 r;
    r[0] = (bf16_t)a[0]; r[1] = (bf16_t)a[1]; r[2] = (bf16_t)a[2]; r[3] = (bf16_t)a[3];
    r[4] = (bf16_t)b[0]; r[5] = (bf16_t)b[1]; r[6] = (bf16_t)b[2]; r[7] = (bf16_t)b[3];
    return r;
}

// ---------------- fp32 -> bf16 convert (elementwise) ----------------
__global__ __launch_bounds__(256) void cvt_bf16(
    const float* __restrict__ src, bf16_t* __restrict__ dst)
{
    size_t i = ((size_t)blockIdx.x * 256 + threadIdx.x) * 8;
    *(bf16x8*)(dst + i) = load_cvt8(src + i);
}

// ---------------- weight transpose+convert: Wt[n][k] = bf16(W[k][n]), 4 mats ----------------
__global__ __launch_bounds__(256) void transpose_w(
    const float* __restrict__ W0, const float* __restrict__ W1,
    const float* __restrict__ W2, const float* __restrict__ W3,
    bf16_t* __restrict__ out)
{
    __shared__ float tile[32][33];
    const float* W = (blockIdx.z == 0) ? W0 : (blockIdx.z == 1) ? W1
                   : (blockIdx.z == 2) ? W2 : W3;
    bf16_t* O = out + (size_t)blockIdx.z * DMODEL * DMODEL;
    int tx = threadIdx.x, ty = threadIdx.y;           // 32 x 8
    int r0 = blockIdx.x * 32, c0 = blockIdx.y * 32;
#pragma unroll
    for (int i = 0; i < 32; i += 8)
        tile[ty + i][tx] = W[(size_t)(r0 + ty + i) * DMODEL + c0 + tx];
    __syncthreads();
#pragma unroll
    for (int i = 0; i < 32; i += 8)
        O[(size_t)(c0 + ty + i) * DMODEL + r0 + tx] = (bf16_t)tile[tx][ty + i];
}

// ---------------- QKV projection GEMM, m97 structure ----------------
// 128x128 tile, BK=32, LDS staged via global_load_lds, 4 waves each 64x64 (4x4 MFMA).
// mode 0: Q -> [B,H,S,Dk] bf16, pre-scaled by 1/8;  mode 1: K -> [B,H,S,Dk];
// mode 2: V -> [B,H,Dk,S] (transposed for PV A-fragments).
__global__ __launch_bounds__(256) void gemm_qkv(
    const bf16_t* __restrict__ Xb, size_t astride, int mode0,
    const bf16_t* __restrict__ Wt,
    const float* __restrict__ bq, const float* __restrict__ bk, const float* __restrict__ bv,
    bf16_t* __restrict__ Qh, bf16_t* __restrict__ Kh, bf16_t* __restrict__ Vt)
{
    const int mode = mode0 + blockIdx.z;
    const bf16_t* A = Xb + astride * (size_t)blockIdx.z;
    const bf16_t* B = Wt + (size_t)mode * DMODEL * DMODEL;
    const float* bias = (mode == 0) ? bq : (mode == 1) ? bk : bv;
    bf16_t* out       = (mode == 0) ? Qh : (mode == 1) ? Kh : Vt;

    __shared__ __align__(16) bf16_t lA[128 * 32];
    __shared__ __align__(16) bf16_t lB[128 * 32];

    const int wave = threadIdx.x >> 6, lane = threadIdx.x & 63;
    const int quad = lane >> 4, l15 = lane & 15;
    const int wm = wave >> 1, wn = wave & 1;
    const int row0 = blockIdx.x * 128, col0 = blockIdx.y * 128;
    const int srow = lane >> 2, scol = (lane & 3) * 8;   // staging: 16 rows/seg, 64B/row

    const floatx4 zero = {0.f, 0.f, 0.f, 0.f};
    floatx4 acc[4][4];
#pragma unroll
    for (int mt = 0; mt < 4; mt++)
#pragma unroll
        for (int nt = 0; nt < 4; nt++) acc[mt][nt] = zero;

    for (int k0 = 0; k0 < DMODEL; k0 += 32) {
#pragma unroll
        for (int j = 0; j < 2; j++) {
            const int seg = j * 4 + wave;
            gload16(A + (size_t)(row0 + seg * 16 + srow) * DMODEL + k0 + scol, lA + seg * 512);
            gload16(B + (size_t)(col0 + seg * 16 + srow) * DMODEL + k0 + scol, lB + seg * 512);
        }
        __syncthreads();   // drains vmcnt(0): LDS tiles complete
        bf16x8 aF[4], bF[4];
#pragma unroll
        for (int t = 0; t < 4; t++) {
            aF[t] = *(const bf16x8*)(lA + (wm * 64 + t * 16 + l15) * 32 + quad * 8);
            bF[t] = *(const bf16x8*)(lB + (wn * 64 + t * 16 + l15) * 32 + quad * 8);
        }
#pragma unroll
        for (int mt = 0; mt < 4; mt++)
#pragma unroll
            for (int nt = 0; nt < 4; nt++)
                acc[mt][nt] = MFMA_BF16(aF[mt], bF[nt], acc[mt][nt]);
        __syncthreads();   // protect LDS before next stage
    }

#pragma unroll
    for (int nt = 0; nt < 4; nt++) {
        const int gn = col0 + wn * 64 + nt * 16 + l15;
        const float bb = bias[gn];
        const int hh = gn >> 6, dd = gn & 63;
#pragma unroll
        for (int mt = 0; mt < 4; mt++) {
#pragma unroll
            for (int r = 0; r < 4; r++) {
                const int tok = row0 + wm * 64 + mt * 16 + quad * 4 + r;
                const int b = tok >> 10, s = tok & 1023;
                float vv = acc[mt][nt][r] + bb;
                size_t addr;
                if (mode == 2) {
                    addr = ((size_t)((b * NHEAD + hh) * HDIM + dd)) * SEQLEN + s;
                } else {
                    if (mode == 0) vv *= 0.125f;  // 1/sqrt(Dk), exact pow2
                    addr = ((size_t)((b * NHEAD + hh) * SEQLEN + s)) * HDIM + dd;
                }
                out[addr] = (bf16_t)vv;
            }
        }
    }
}

// ---------------- output projection GEMM (bf16 A/B, fp32 bias+out) ----------------
__global__ __launch_bounds__(256) void gemm_o(
    const bf16_t* __restrict__ Xa, const bf16_t* __restrict__ Wt,
    const float* __restrict__ bias, float* __restrict__ out)
{
    __shared__ __align__(16) bf16_t lA[128 * 32];
    __shared__ __align__(16) bf16_t lB[128 * 32];

    const int wave = threadIdx.x >> 6, lane = threadIdx.x & 63;
    const int quad = lane >> 4, l15 = lane & 15;
    const int wm = wave >> 1, wn = wave & 1;
    const int row0 = blockIdx.x * 128, col0 = blockIdx.y * 128;
    const int srow = lane >> 2, scol = (lane & 3) * 8;

    const floatx4 zero = {0.f, 0.f, 0.f, 0.f};
    floatx4 acc[4][4];
#pragma unroll
    for (int mt = 0; mt < 4; mt++)
#pragma unroll
        for (int nt = 0; nt < 4; nt++) acc[mt][nt] = zero;

    for (int k0 = 0; k0 < DMODEL; k0 += 32) {
#pragma unroll
        for (int j = 0; j < 2; j++) {
            const int seg = j * 4 + wave;
            gload16(Xa + (size_t)(row0 + seg * 16 + srow) * DMODEL + k0 + scol, lA + seg * 512);
            gload16(Wt + (size_t)(col0 + seg * 16 + srow) * DMODEL + k0 + scol, lB + seg * 512);
        }
        __syncthreads();
        bf16x8 aF[4], bF[4];
#pragma unroll
        for (int t = 0; t < 4; t++) {
            aF[t] = *(const bf16x8*)(lA + (wm * 64 + t * 16 + l15) * 32 + quad * 8);
            bF[t] = *(const bf16x8*)(lB + (wn * 64 + t * 16 + l15) * 32 + quad * 8);
        }
#pragma unroll
        for (int mt = 0; mt < 4; mt++)
#pragma unroll
            for (int nt = 0; nt < 4; nt++)
                acc[mt][nt] = MFMA_BF16(aF[mt], bF[nt], acc[mt][nt]);
        __syncthreads();
    }

#pragma unroll
    for (int nt = 0; nt < 4; nt++) {
        const int gn = col0 + wn * 64 + nt * 16 + l15;
        const float bb = bias[gn];
#pragma unroll
        for (int mt = 0; mt < 4; mt++) {
#pragma unroll
            for (int r = 0; r < 4; r++) {
                const int tok = row0 + wm * 64 + mt * 16 + quad * 4 + r;
                out[(size_t)tok * DMODEL + gn] = acc[mt][nt][r] + bb;
            }
        }
    }
}

// ---------------- causal flash attention, transposed-S formulation ----------------
// S^T = mfma(A=K[key][d], B=Q[qrow][d]) -> C col(l15)=qrow, rows=keys.
// Per-lane online-softmax state (one m,l per lane); P packed ds_write_b64;
// O^T = mfma(A=V^T[d][key], B=P[qrow][key]).  grid: (S/64, B*H), wave = 16 qrows.
__global__ __launch_bounds__(256) void attn(
    const bf16_t* __restrict__ Qh, const bf16_t* __restrict__ Kh,
    const bf16_t* __restrict__ Vt, bf16_t* __restrict__ X)
{
    __shared__ __align__(16) bf16_t plds[4][16 * 40];  // per-wave P tile [qrow][key], stride 40
    const int wave = threadIdx.x >> 6, lane = threadIdx.x & 63;
    const int quad = lane >> 4, l15 = lane & 15;
    const int bh = blockIdx.y, b = bh >> 4, h = bh & 15;
    const int qbase = blockIdx.x * 64 + wave * 16;
    const int qrow = qbase + l15;                     // this lane's query row (fixed)
    const bf16_t* Qp = Qh + (size_t)bh * SEQLEN * HDIM;
    const bf16_t* Kp = Kh + (size_t)bh * SEQLEN * HDIM;
    const bf16_t* Vp = Vt + (size_t)bh * HDIM * SEQLEN;
    bf16_t* pl = plds[wave];

    bf16x8 bQ[2];
#pragma unroll
    for (int c = 0; c < 2; c++)
        bQ[c] = *(const bf16x8*)(Qp + (size_t)(qbase + l15) * HDIM + c * 32 + quad * 8);

    const floatx4 zero = {0.f, 0.f, 0.f, 0.f};
    float m_s = -INFINITY, l_s = 0.f;
    floatx4 accO[4];
#pragma unroll
    for (int dt = 0; dt < 4; dt++) accO[dt] = zero;

    const int nk = (qbase + 47) >> 5;  // key chunks of 32; kb_max <= qbase always
    for (int kc = 0; kc < nk; kc++) {
        const int kb = kc * 32;
        floatx4 S0 = zero, S1 = zero;
#pragma unroll
        for (int c = 0; c < 2; c++) {
            bf16x8 aK0 = *(const bf16x8*)(Kp + (size_t)(kb + l15) * HDIM + c * 32 + quad * 8);
            bf16x8 aK1 = *(const bf16x8*)(Kp + (size_t)(kb + 16 + l15) * HDIM + c * 32 + quad * 8);
            S0 = MFMA_BF16(aK0, bQ[c], S0);
            S1 = MFMA_BF16(aK1, bQ[c], S1);
        }
        float s0a[4], s1a[4];
        float mx = -1e30f;
#pragma unroll
        for (int r = 0; r < 4; r++) {
            const int key0 = kb + quad * 4 + r;       // S^T row -> key index
            s0a[r] = (key0 <= qrow)      ? S0[r] : -1e30f;
            s1a[r] = (key0 + 16 <= qrow) ? S1[r] : -1e30f;
            mx = fmaxf(mx, fmaxf(s0a[r], s1a[r]));
        }
        mx = fmaxf(mx, __shfl_xor(mx, 16));
        mx = fmaxf(mx, __shfl_xor(mx, 32));
        const float mn = fmaxf(m_s, mx);
        const float alpha = __expf(m_s - mn);
        m_s = mn;
        bf16x4 p0, p1;
        float ps = 0.f;
#pragma unroll
        for (int r = 0; r < 4; r++) {
            float e0 = __expf(s0a[r] - mn);
            float e1 = __expf(s1a[r] - mn);
            ps += e0 + e1;
            p0[r] = (bf16_t)e0; p1[r] = (bf16_t)e1;
        }
        ps += __shfl_xor(ps, 16);
        ps += __shfl_xor(ps, 32);
        l_s = l_s * alpha + ps;
#pragma unroll
        for (int dt = 0; dt < 4; dt++)
#pragma unroll
            for (int r = 0; r < 4; r++) accO[dt][r] *= alpha;
        // P C-layout regs are 4 consecutive keys -> packed 8B writes; [qrow][key] in LDS
        *(bf16x4*)(pl + l15 * 40 + quad * 4)      = p0;
        *(bf16x4*)(pl + l15 * 40 + 16 + quad * 4) = p1;
        bf16x8 bP = *(const bf16x8*)(pl + l15 * 40 + quad * 8);  // B[n=qrow][k=key]
#pragma unroll
        for (int dt = 0; dt < 4; dt++) {
            bf16x8 aV = *(const bf16x8*)(Vp + (size_t)(dt * 16 + l15) * SEQLEN + kb + quad * 8);
            accO[dt] = MFMA_BF16(aV, bP, accO[dt]);
        }
    }

    const float inv = 1.f / l_s;
#pragma unroll
    for (int dt = 0; dt < 4; dt++) {
        bf16x4 o;
#pragma unroll
        for (int r = 0; r < 4; r++) o[r] = (bf16_t)(accO[dt][r] * inv);
        *(bf16x4*)(&X[((size_t)(b * SEQLEN + qrow)) * DMODEL + h * HDIM + dt * 16 + quad * 4]) = o;
    }
}

extern "C" void kernel_launch(void* const* d_in, const int* in_sizes, int n_in,
                              void* d_out, int out_size, void* d_ws, size_t ws_size,
                              hipStream_t stream)
{
    const float* qkv_in[3] = {(const float*)d_in[0], (const float*)d_in[1], (const float*)d_in[2]};
    // d_in[3] = causal mask (deterministic tril) — applied analytically
    const float* Wq = (const float*)d_in[4];
    const float* bq = (const float*)d_in[5];
    const float* Wk = (const float*)d_in[6];
    const float* bk = (const float*)d_in[7];
    const float* Wv = (const float*)d_in[8];
    const float* bv = (const float*)d_in[9];
    const float* Wo = (const float*)d_in[10];
    const float* bo = (const float*)d_in[11];
    float* out = (float*)d_out;

    char* ws = (char*)d_ws;
    const size_t MB = 1ull << 20;
    const size_t NELEM = (size_t)NTOK * DMODEL;            // 4M elements / 8 MB bf16
    bf16_t* Wt = (bf16_t*)ws;                              // [0,8) MB: 4 transposed bf16 weights
    bf16_t* Qh = (bf16_t*)(ws + 8 * MB);                   // [8,16)
    bf16_t* Kh = (bf16_t*)(ws + 16 * MB);                  // [16,24)
    bf16_t* Vt = (bf16_t*)(ws + 24 * MB);                  // [24,32)
    bf16_t* Xr = (bf16_t*)(ws + 32 * MB);                  // [32,...) bf16 staging; Xa overlays

    transpose_w<<<dim3(32, 32, 4), dim3(32, 8), 0, stream>>>(Wq, Wk, Wv, Wo, Wt);

    if (ws_size >= 56 * MB) {
        // fused: convert all three, one 768-block GEMM launch (3 blocks/CU)
        for (int m = 0; m < 3; m++)
            cvt_bf16<<<dim3(2048), dim3(256), 0, stream>>>(qkv_in[m], Xr + m * NELEM);
        gemm_qkv<<<dim3(32, 8, 3), dim3(256), 0, stream>>>(
            Xr, NELEM, 0, Wt, bq, bk, bv, Qh, Kh, Vt);
    } else {
        // serialized: reuse one 8 MB staging buffer (40 MB total)
        for (int m = 0; m < 3; m++) {
            cvt_bf16<<<dim3(2048), dim3(256), 0, stream>>>(qkv_in[m], Xr);
            gemm_qkv<<<dim3(32, 8, 1), dim3(256), 0, stream>>>(
                Xr, 0, m, Wt, bq, bk, bv, Qh, Kh, Vt);
        }
    }

    // attn writes Xa over Xr[0..8MB) (q's bf16 copy, dead after gemm_qkv)
    bf16_t* Xa = Xr;
    attn<<<dim3(16, 64), dim3(256), 0, stream>>>(Qh, Kh, Vt, Xa);
    gemm_o<<<dim3(32, 8), dim3(256), 0, stream>>>(
        Xa, Wt + 3 * (size_t)DMODEL * DMODEL, bo, out);
}

// Round 5
// 255.900 us; speedup vs baseline: 2.1150x; 1.2488x over previous
//
#include <hip/hip_runtime.h>
#include <math.h>

typedef __bf16 bf16_t;
typedef bf16_t bf16x8 __attribute__((ext_vector_type(8)));
typedef bf16_t bf16x4 __attribute__((ext_vector_type(4)));
typedef float  floatx4 __attribute__((ext_vector_type(4)));
typedef unsigned int u32;

#define MFMA_BF16(a, b, c) __builtin_amdgcn_mfma_f32_16x16x32_bf16((a), (b), (c), 0, 0, 0)

static constexpr int DMODEL = 1024;
static constexpr int NHEAD  = 16;
static constexpr int HDIM   = 64;
static constexpr int NBATCH = 4;
static constexpr int SEQLEN = 1024;
static constexpr int NTOK   = NBATCH * SEQLEN;  // 4096

typedef __attribute__((address_space(3))) void       as3_void;
typedef __attribute__((address_space(1))) const void as1_cvoid;

// async global->LDS, 16B per lane; LDS dest = wave-uniform base + lane*16
__device__ __forceinline__ void gload16(const bf16_t* g, bf16_t* l) {
    __builtin_amdgcn_global_load_lds((as1_cvoid*)g, (as3_void*)l, 16, 0, 0);
}

// load 8 consecutive fp32, round to bf16x8
__device__ __forceinline__ bf16x8 load_cvt8(const float* __restrict__ p) {
    floatx4 a = *(const floatx4*)p;
    floatx4 b = *(const floatx4*)(p + 4);
    bf16x8 r;
    r[0] = (bf16_t)a[0]; r[1] = (bf16_t)a[1]; r[2] = (bf16_t)a[2]; r[3] = (bf16_t)a[3];
    r[4] = (bf16_t)b[0]; r[5] = (bf16_t)b[1]; r[6] = (bf16_t)b[2]; r[7] = (bf16_t)b[3];
    return r;
}

// ---------------- fp32 -> bf16 convert, 3 tensors in one launch ----------------
__global__ __launch_bounds__(256) void cvt3_bf16(
    const float* __restrict__ s0, const float* __restrict__ s1, const float* __restrict__ s2,
    bf16_t* __restrict__ dst, size_t dstride)
{
    const float* src = (blockIdx.y == 0) ? s0 : (blockIdx.y == 1) ? s1 : s2;
    size_t i = ((size_t)blockIdx.x * 256 + threadIdx.x) * 8;
    *(bf16x8*)(dst + blockIdx.y * dstride + i) = load_cvt8(src + i);
}
__global__ __launch_bounds__(256) void cvt_bf16(
    const float* __restrict__ src, bf16_t* __restrict__ dst)
{
    size_t i = ((size_t)blockIdx.x * 256 + threadIdx.x) * 8;
    *(bf16x8*)(dst + i) = load_cvt8(src + i);
}

// ---------------- weight transpose+convert: Wt[n][k] = bf16(W[k][n]), 4 mats ----------------
__global__ __launch_bounds__(256) void transpose_w(
    const float* __restrict__ W0, const float* __restrict__ W1,
    const float* __restrict__ W2, const float* __restrict__ W3,
    bf16_t* __restrict__ out)
{
    __shared__ float tile[32][33];
    const float* W = (blockIdx.z == 0) ? W0 : (blockIdx.z == 1) ? W1
                   : (blockIdx.z == 2) ? W2 : W3;
    bf16_t* O = out + (size_t)blockIdx.z * DMODEL * DMODEL;
    int tx = threadIdx.x, ty = threadIdx.y;           // 32 x 8
    int r0 = blockIdx.x * 32, c0 = blockIdx.y * 32;
#pragma unroll
    for (int i = 0; i < 32; i += 8)
        tile[ty + i][tx] = W[(size_t)(r0 + ty + i) * DMODEL + c0 + tx];
    __syncthreads();
#pragma unroll
    for (int i = 0; i < 32; i += 8)
        O[(size_t)(c0 + ty + i) * DMODEL + r0 + tx] = (bf16_t)tile[tx][ty + i];
}

// ---------------- QKV projection GEMM, 128x128 tile, BK=32 ----------------
__global__ __launch_bounds__(256) void gemm_qkv(
    const bf16_t* __restrict__ Xb, size_t astride, int mode0,
    const bf16_t* __restrict__ Wt,
    const float* __restrict__ bq, const float* __restrict__ bk, const float* __restrict__ bv,
    bf16_t* __restrict__ Qh, bf16_t* __restrict__ Kh, bf16_t* __restrict__ Vt)
{
    const int mode = mode0 + blockIdx.z;
    const bf16_t* A = Xb + astride * (size_t)blockIdx.z;
    const bf16_t* B = Wt + (size_t)mode * DMODEL * DMODEL;
    const float* bias = (mode == 0) ? bq : (mode == 1) ? bk : bv;
    bf16_t* out       = (mode == 0) ? Qh : (mode == 1) ? Kh : Vt;

    __shared__ __align__(16) bf16_t lA[128 * 32];
    __shared__ __align__(16) bf16_t lB[128 * 32];

    const int wave = threadIdx.x >> 6, lane = threadIdx.x & 63;
    const int quad = lane >> 4, l15 = lane & 15;
    const int wm = wave >> 1, wn = wave & 1;
    const int row0 = blockIdx.x * 128, col0 = blockIdx.y * 128;
    const int srow = lane >> 2, scol = (lane & 3) * 8;

    const floatx4 zero = {0.f, 0.f, 0.f, 0.f};
    floatx4 acc[4][4];
#pragma unroll
    for (int mt = 0; mt < 4; mt++)
#pragma unroll
        for (int nt = 0; nt < 4; nt++) acc[mt][nt] = zero;

    for (int k0 = 0; k0 < DMODEL; k0 += 32) {
#pragma unroll
        for (int j = 0; j < 2; j++) {
            const int seg = j * 4 + wave;
            gload16(A + (size_t)(row0 + seg * 16 + srow) * DMODEL + k0 + scol, lA + seg * 512);
            gload16(B + (size_t)(col0 + seg * 16 + srow) * DMODEL + k0 + scol, lB + seg * 512);
        }
        __syncthreads();
        bf16x8 aF[4], bF[4];
#pragma unroll
        for (int t = 0; t < 4; t++) {
            aF[t] = *(const bf16x8*)(lA + (wm * 64 + t * 16 + l15) * 32 + quad * 8);
            bF[t] = *(const bf16x8*)(lB + (wn * 64 + t * 16 + l15) * 32 + quad * 8);
        }
#pragma unroll
        for (int mt = 0; mt < 4; mt++)
#pragma unroll
            for (int nt = 0; nt < 4; nt++)
                acc[mt][nt] = MFMA_BF16(aF[mt], bF[nt], acc[mt][nt]);
        __syncthreads();
    }

#pragma unroll
    for (int nt = 0; nt < 4; nt++) {
        const int gn = col0 + wn * 64 + nt * 16 + l15;
        const float bb = bias[gn];
        const int hh = gn >> 6, dd = gn & 63;
#pragma unroll
        for (int mt = 0; mt < 4; mt++) {
#pragma unroll
            for (int r = 0; r < 4; r++) {
                const int tok = row0 + wm * 64 + mt * 16 + quad * 4 + r;
                const int b = tok >> 10, s = tok & 1023;
                float vv = acc[mt][nt][r] + bb;
                size_t addr;
                if (mode == 2) {
                    addr = ((size_t)((b * NHEAD + hh) * HDIM + dd)) * SEQLEN + s;
                } else {
                    if (mode == 0) vv *= 0.125f;  // 1/sqrt(Dk), exact pow2
                    addr = ((size_t)((b * NHEAD + hh) * SEQLEN + s)) * HDIM + dd;
                }
                out[addr] = (bf16_t)vv;
            }
        }
    }
}

// ---------------- output projection GEMM, 64x128 tile (512 blocks = 2/CU) ----------------
__global__ __launch_bounds__(256) void gemm_o(
    const bf16_t* __restrict__ Xa, const bf16_t* __restrict__ Wt,
    const float* __restrict__ bias, float* __restrict__ out)
{
    __shared__ __align__(16) bf16_t lA[64 * 32];
    __shared__ __align__(16) bf16_t lB[128 * 32];

    const int wave = threadIdx.x >> 6, lane = threadIdx.x & 63;
    const int quad = lane >> 4, l15 = lane & 15;
    const int wm = wave & 1, wn = wave >> 1;       // 2 m-halves x 2 n-halves
    const int row0 = blockIdx.x * 64, col0 = blockIdx.y * 128;
    const int srow = lane >> 2, scol = (lane & 3) * 8;

    const floatx4 zero = {0.f, 0.f, 0.f, 0.f};
    floatx4 acc[2][4];
#pragma unroll
    for (int mt = 0; mt < 2; mt++)
#pragma unroll
        for (int nt = 0; nt < 4; nt++) acc[mt][nt] = zero;

    for (int k0 = 0; k0 < DMODEL; k0 += 32) {
        // lA: 4 segs (one per wave); lB: 8 segs (two per wave)
        gload16(Xa + (size_t)(row0 + wave * 16 + srow) * DMODEL + k0 + scol, lA + wave * 512);
#pragma unroll
        for (int j = 0; j < 2; j++) {
            const int seg = wave * 2 + j;
            gload16(Wt + (size_t)(col0 + seg * 16 + srow) * DMODEL + k0 + scol, lB + seg * 512);
        }
        __syncthreads();
        bf16x8 aF[2], bF[4];
#pragma unroll
        for (int t = 0; t < 2; t++)
            aF[t] = *(const bf16x8*)(lA + (wm * 32 + t * 16 + l15) * 32 + quad * 8);
#pragma unroll
        for (int t = 0; t < 4; t++)
            bF[t] = *(const bf16x8*)(lB + (wn * 64 + t * 16 + l15) * 32 + quad * 8);
#pragma unroll
        for (int mt = 0; mt < 2; mt++)
#pragma unroll
            for (int nt = 0; nt < 4; nt++)
                acc[mt][nt] = MFMA_BF16(aF[mt], bF[nt], acc[mt][nt]);
        __syncthreads();
    }

#pragma unroll
    for (int nt = 0; nt < 4; nt++) {
        const int gn = col0 + wn * 64 + nt * 16 + l15;
        const float bb = bias[gn];
#pragma unroll
        for (int mt = 0; mt < 2; mt++) {
#pragma unroll
            for (int r = 0; r < 4; r++) {
                const int tok = row0 + wm * 32 + mt * 16 + quad * 4 + r;
                out[(size_t)tok * DMODEL + gn] = acc[mt][nt][r] + bb;
            }
        }
    }
}

// ---------------- causal flash attention: dual-stream, pair-balanced, no LDS ----------------
// Each wave owns q-tiles t and 63-t of one (b,h): total chunks/wave = 33..34 (balanced).
// S^T = mfma(A=K, B=Q); per-lane online softmax (qrow = l15); P transposed to the
// PV B-fragment layout via 8 shuffles; O^T = mfma(A=V^T, B=P).
// K/V fragment loads are shared by both streams. XCD swizzle: 8 heads per XCD.
__global__ __launch_bounds__(256) void attn(
    const bf16_t* __restrict__ Qh, const bf16_t* __restrict__ Kh,
    const bf16_t* __restrict__ Vt, bf16_t* __restrict__ X)
{
    const int wave = threadIdx.x >> 6, lane = threadIdx.x & 63;
    const int quad = lane >> 4, l15 = lane & 15;
    const int L = blockIdx.x;                          // [0,512)
    const int bh = (L & 7) * 8 + ((L >> 3) & 7);       // same 8 heads stay on one XCD
    const int pb = L >> 6;                             // [0,8)
    const int t  = pb * 4 + wave;                      // pair index [0,32)
    const int b = bh >> 4, h = bh & 15;

    const int qbaseA = 16 * t, qbaseB = 1008 - 16 * t;
    const int qrowA = qbaseA + l15, qrowB = qbaseB + l15;
    // nkA = ceil((qbaseA+16)/32) = t/2+1 (exact both parities)
    // nkB = ceil((qbaseB+16)/32) = ceil(32 - t/2) = 32 - t/2 (int div)  [round-4 bug: was 32-(t+1)/2]
    const int nkA = t / 2 + 1, nkB = 32 - t / 2;

    const bf16_t* Qp = Qh + (size_t)bh * SEQLEN * HDIM;
    const bf16_t* Kp = Kh + (size_t)bh * SEQLEN * HDIM;
    const bf16_t* Vp = Vt + (size_t)bh * HDIM * SEQLEN;

    bf16x8 bQA[2], bQB[2];
#pragma unroll
    for (int c = 0; c < 2; c++) {
        bQA[c] = *(const bf16x8*)(Qp + (size_t)qrowA * HDIM + c * 32 + quad * 8);
        bQB[c] = *(const bf16x8*)(Qp + (size_t)qrowB * HDIM + c * 32 + quad * 8);
    }

    const floatx4 zero = {0.f, 0.f, 0.f, 0.f};
    float mA = -INFINITY, lA_ = 0.f, mB = -INFINITY, lB_ = 0.f;
    floatx4 oA[4], oB[4];
#pragma unroll
    for (int dt = 0; dt < 4; dt++) { oA[dt] = zero; oB[dt] = zero; }

    const int srcA = ((quad & 1) ? 32 : 0) + l15;      // P-transpose shuffle sources
    const int srcB = srcA + 16;
    const bool hiP = (quad >= 2);

    for (int kc = 0; kc < nkB; kc++) {
        const int kb = kc * 32;
        // shared K fragments (A-layout) and V^T fragments
        bf16x8 aK0[2], aK1[2], aV[4];
#pragma unroll
        for (int c = 0; c < 2; c++) {
            aK0[c] = *(const bf16x8*)(Kp + (size_t)(kb + l15) * HDIM + c * 32 + quad * 8);
            aK1[c] = *(const bf16x8*)(Kp + (size_t)(kb + 16 + l15) * HDIM + c * 32 + quad * 8);
        }
#pragma unroll
        for (int dt = 0; dt < 4; dt++)
            aV[dt] = *(const bf16x8*)(Vp + (size_t)(dt * 16 + l15) * SEQLEN + kb + quad * 8);

        const bool doA = (kc < nkA);                   // wave-uniform

        floatx4 S0B = zero, S1B = zero, S0A = zero, S1A = zero;
#pragma unroll
        for (int c = 0; c < 2; c++) {
            S0B = MFMA_BF16(aK0[c], bQB[c], S0B);
            S1B = MFMA_BF16(aK1[c], bQB[c], S1B);
        }
        if (doA) {
#pragma unroll
            for (int c = 0; c < 2; c++) {
                S0A = MFMA_BF16(aK0[c], bQA[c], S0A);
                S1A = MFMA_BF16(aK1[c], bQA[c], S1A);
            }
        }

        // ---- stream B softmax + PV ----
        {
            float s0[4], s1[4], mx = -1e30f;
#pragma unroll
            for (int r = 0; r < 4; r++) {
                const int key0 = kb + quad * 4 + r;
                s0[r] = (key0 <= qrowB)      ? S0B[r] : -1e30f;
                s1[r] = (key0 + 16 <= qrowB) ? S1B[r] : -1e30f;
                mx = fmaxf(mx, fmaxf(s0[r], s1[r]));
            }
            mx = fmaxf(mx, __shfl_xor(mx, 16));
            mx = fmaxf(mx, __shfl_xor(mx, 32));
            const float mn = fmaxf(mB, mx);
            const float alpha = __expf(mB - mn);
            mB = mn;
            float ps = 0.f;
            union { bf16_t hh2[8]; u32 u[4]; } pk;
#pragma unroll
            for (int r = 0; r < 4; r++) {
                float e0 = __expf(s0[r] - mn), e1 = __expf(s1[r] - mn);
                ps += e0 + e1;
                pk.hh2[r] = (bf16_t)e0; pk.hh2[4 + r] = (bf16_t)e1;
            }
            ps += __shfl_xor(ps, 16);
            ps += __shfl_xor(ps, 32);
            lB_ = lB_ * alpha + ps;
#pragma unroll
            for (int dt = 0; dt < 4; dt++)
#pragma unroll
                for (int r = 0; r < 4; r++) oB[dt][r] *= alpha;
            u32 a0 = __shfl(pk.u[0], srcA), a1 = __shfl(pk.u[1], srcA);
            u32 a2 = __shfl(pk.u[0], srcB), a3 = __shfl(pk.u[1], srcB);
            u32 b0 = __shfl(pk.u[2], srcA), b1 = __shfl(pk.u[3], srcA);
            u32 b2 = __shfl(pk.u[2], srcB), b3 = __shfl(pk.u[3], srcB);
            union { u32 u[4]; bf16x8 v; } bP;
            bP.u[0] = hiP ? b0 : a0; bP.u[1] = hiP ? b1 : a1;
            bP.u[2] = hiP ? b2 : a2; bP.u[3] = hiP ? b3 : a3;
#pragma unroll
            for (int dt = 0; dt < 4; dt++) oB[dt] = MFMA_BF16(aV[dt], bP.v, oB[dt]);
        }

        // ---- stream A softmax + PV ----
        if (doA) {
            float s0[4], s1[4], mx = -1e30f;
#pragma unroll
            for (int r = 0; r < 4; r++) {
                const int key0 = kb + quad * 4 + r;
                s0[r] = (key0 <= qrowA)      ? S0A[r] : -1e30f;
                s1[r] = (key0 + 16 <= qrowA) ? S1A[r] : -1e30f;
                mx = fmaxf(mx, fmaxf(s0[r], s1[r]));
            }
            mx = fmaxf(mx, __shfl_xor(mx, 16));
            mx = fmaxf(mx, __shfl_xor(mx, 32));
            const float mn = fmaxf(mA, mx);
            const float alpha = __expf(mA - mn);
            mA = mn;
            float ps = 0.f;
            union { bf16_t hh2[8]; u32 u[4]; } pk;
#pragma unroll
            for (int r = 0; r < 4; r++) {
                float e0 = __expf(s0[r] - mn), e1 = __expf(s1[r] - mn);
                ps += e0 + e1;
                pk.hh2[r] = (bf16_t)e0; pk.hh2[4 + r] = (bf16_t)e1;
            }
            ps += __shfl_xor(ps, 16);
            ps += __shfl_xor(ps, 32);
            lA_ = lA_ * alpha + ps;
#pragma unroll
            for (int dt = 0; dt < 4; dt++)
#pragma unroll
                for (int r = 0; r < 4; r++) oA[dt][r] *= alpha;
            u32 a0 = __shfl(pk.u[0], srcA), a1 = __shfl(pk.u[1], srcA);
            u32 a2 = __shfl(pk.u[0], srcB), a3 = __shfl(pk.u[1], srcB);
            u32 b0 = __shfl(pk.u[2], srcA), b1 = __shfl(pk.u[3], srcA);
            u32 b2 = __shfl(pk.u[2], srcB), b3 = __shfl(pk.u[3], srcB);
            union { u32 u[4]; bf16x8 v; } bP;
            bP.u[0] = hiP ? b0 : a0; bP.u[1] = hiP ? b1 : a1;
            bP.u[2] = hiP ? b2 : a2; bP.u[3] = hiP ? b3 : a3;
#pragma unroll
            for (int dt = 0; dt < 4; dt++) oA[dt] = MFMA_BF16(aV[dt], bP.v, oA[dt]);
        }
    }

    const float invA = 1.f / lA_, invB = 1.f / lB_;
#pragma unroll
    for (int dt = 0; dt < 4; dt++) {
        bf16x4 va, vb;
#pragma unroll
        for (int r = 0; r < 4; r++) {
            va[r] = (bf16_t)(oA[dt][r] * invA);
            vb[r] = (bf16_t)(oB[dt][r] * invB);
        }
        const size_t cofs = (size_t)h * HDIM + dt * 16 + quad * 4;
        *(bf16x4*)(&X[((size_t)(b * SEQLEN + qrowA)) * DMODEL + cofs]) = va;
        *(bf16x4*)(&X[((size_t)(b * SEQLEN + qrowB)) * DMODEL + cofs]) = vb;
    }
}

extern "C" void kernel_launch(void* const* d_in, const int* in_sizes, int n_in,
                              void* d_out, int out_size, void* d_ws, size_t ws_size,
                              hipStream_t stream)
{
    const float* qkv_in[3] = {(const float*)d_in[0], (const float*)d_in[1], (const float*)d_in[2]};
    // d_in[3] = causal mask (deterministic tril) — applied analytically
    const float* Wq = (const float*)d_in[4];
    const float* bq = (const float*)d_in[5];
    const float* Wk = (const float*)d_in[6];
    const float* bk = (const float*)d_in[7];
    const float* Wv = (const float*)d_in[8];
    const float* bv = (const float*)d_in[9];
    const float* Wo = (const float*)d_in[10];
    const float* bo = (const float*)d_in[11];
    float* out = (float*)d_out;

    char* ws = (char*)d_ws;
    const size_t MB = 1ull << 20;
    const size_t NELEM = (size_t)NTOK * DMODEL;            // 4M elements / 8 MB bf16
    bf16_t* Wt = (bf16_t*)ws;                              // [0,8) MB: 4 transposed bf16 weights
    bf16_t* Qh = (bf16_t*)(ws + 8 * MB);                   // [8,16)
    bf16_t* Kh = (bf16_t*)(ws + 16 * MB);                  // [16,24)
    bf16_t* Vt = (bf16_t*)(ws + 24 * MB);                  // [24,32)
    bf16_t* Xr = (bf16_t*)(ws + 32 * MB);                  // [32,...) bf16 staging; Xa overlays

    transpose_w<<<dim3(32, 32, 4), dim3(32, 8), 0, stream>>>(Wq, Wk, Wv, Wo, Wt);

    if (ws_size >= 56 * MB) {
        cvt3_bf16<<<dim3(2048, 3), dim3(256), 0, stream>>>(
            qkv_in[0], qkv_in[1], qkv_in[2], Xr, NELEM);
        gemm_qkv<<<dim3(32, 8, 3), dim3(256), 0, stream>>>(
            Xr, NELEM, 0, Wt, bq, bk, bv, Qh, Kh, Vt);
    } else {
        for (int m = 0; m < 3; m++) {
            cvt_bf16<<<dim3(2048), dim3(256), 0, stream>>>(qkv_in[m], Xr);
            gemm_qkv<<<dim3(32, 8, 1), dim3(256), 0, stream>>>(
                Xr, 0, m, Wt, bq, bk, bv, Qh, Kh, Vt);
        }
    }

    // attn writes Xa over Xr[0..8MB) (q's bf16 copy, dead after gemm_qkv)
    bf16_t* Xa = Xr;
    attn<<<dim3(512), dim3(256), 0, stream>>>(Qh, Kh, Vt, Xa);
    gemm_o<<<dim3(64, 8), dim3(256), 0, stream>>>(
        Xa, Wt + 3 * (size_t)DMODEL * DMODEL, bo, out);
}